// Round 1
// 345.803 us; speedup vs baseline: 1.2822x; 1.2822x over previous
//
#include <hip/hip_runtime.h>

#define S_SCALE 30.0f
#define COS_M 0.8775825618903728f
#define SIN_M 0.479425538604203f
#define TH_C (-0.8775825618903728f)
#define MM_C 0.2397127693021015f

#define BD 512
#define DD 512
#define CC 100000
#define NCB 1563            // ceil(100000/64)
#define LASTB 1562

typedef __bf16 bf16x8 __attribute__((ext_vector_type(8)));
typedef __bf16 bf16x4 __attribute__((ext_vector_type(4)));
typedef float  f32x4  __attribute__((ext_vector_type(4)));

#define AS1 __attribute__((address_space(1)))
#define AS3 __attribute__((address_space(3)))

// ---------------- Kernel 1: concat + normalize -> k-tiled bf16 A_t[16][512][32];
// also label-column cosine/phi. ----------------
__global__ __launch_bounds__(256) void k_prep(const float* __restrict__ img,
                                              const float* __restrict__ prof,
                                              const float* __restrict__ W,
                                              const int* __restrict__ lab,
                                              __bf16* __restrict__ At,
                                              float* __restrict__ sphi,
                                              float* __restrict__ scos) {
    const int row = blockIdx.x;
    const int t = threadIdx.x;
    const float* src = (row < 256) ? (img + (size_t)row * DD) : (prof + (size_t)(row - 256) * DD);
    float x0 = src[t], x1 = src[t + 256];
    float s = x0 * x0 + x1 * x1;
    for (int o = 1; o < 64; o <<= 1) s += __shfl_xor(s, o);
    __shared__ float ws4[4];
    if ((t & 63) == 0) ws4[t >> 6] = s;
    __syncthreads();
    float r = rsqrtf(ws4[0] + ws4[1] + ws4[2] + ws4[3]);
    __bf16 a0 = (__bf16)(x0 * r), a1 = (__bf16)(x1 * r);
    // k-tiled layout: element (row, d) -> At[(d>>5)*16384 + row*32 + (d&31)]
    At[(size_t)(t >> 5) * (BD * 32) + row * 32 + (t & 31)]           = a0;
    At[(size_t)((t + 256) >> 5) * (BD * 32) + row * 32 + (t & 31)]   = a1;

    // label-column cosine (on bf16-truncated values, matching the GEMM)
    const int c = lab[row & 255];
    float w0 = (float)(__bf16)W[(size_t)c * DD + t];
    float w1 = (float)(__bf16)W[(size_t)c * DD + t + 256];
    float dot = (float)a0 * w0 + (float)a1 * w1;
    float wsq = w0 * w0 + w1 * w1;
    for (int o = 1; o < 64; o <<= 1) { dot += __shfl_xor(dot, o); wsq += __shfl_xor(wsq, o); }
    __shared__ float sd[4], sw[4];
    if ((t & 63) == 0) { sd[t >> 6] = dot; sw[t >> 6] = wsq; }
    __syncthreads();
    if (t == 0) {
        float D = sd[0] + sd[1] + sd[2] + sd[3];
        float Q = sw[0] + sw[1] + sw[2] + sw[3];
        float cs = D * rsqrtf(Q);
        float sn = sqrtf(fmaxf(0.f, fminf(1.f, 1.f - cs * cs)));
        float phi = cs * COS_M - sn * SIN_M;
        if (!(cs > TH_C)) phi = cs - MM_C;
        sphi[row] = S_SCALE * phi;
        scos[row] = S_SCALE * cs;
    }
}

// ---------------- Kernel 2: MFMA GEMM, 512 rows x 64 cols per block ----------------
// Counted-vmcnt pipeline (raw s_barrier, never drains the W prefetch stream),
// XOR-swizzled LDS chunks (swizzle applied to glds SOURCE + ds_read addr; LDS linear).
__global__ __launch_bounds__(256, 2) void k_gemm(const __bf16* __restrict__ At,
                                                 const float* __restrict__ W,
                                                 float* __restrict__ part) {
    __shared__ __bf16 As[2][BD * 32];    // 2 x 32 KB, linear (glds dest)
    __shared__ __bf16 Bs[2][64 * 32];    // 2 x 4 KB
    __shared__ float  csq[64];

    const int t = threadIdx.x;
    const int cb = blockIdx.x;
    const int wave = t >> 6, lane = t & 63, q = lane >> 4, m16 = lane & 15;

    // chunk swizzle: 16B chunk (row, s) stored at LDS chunk row*4 + (s ^ ((row>>1)&3))
    // glds source pre-swizzle (per-lane): chunk c = c8*256 + t
    const int srcswz  = ((t >> 2) << 6) + ((((t & 3) ^ ((t >> 3) & 3))) << 4);   // bytes
    // fragment read offset (elements) for logical (row = ..+m16, kchunk q):
    const int frag_off = m16 * 32 + ((q ^ ((m16 >> 1) & 3)) << 3);

    // W staging: thread t covers (col t>>3, kc t&7) and (col 32+(t>>3), kc t&7)
    const int wcol = t >> 3, kc = t & 7;
    int gc0 = cb * 64 + wcol;
    int gc1 = gc0 + 32;
    const float* wp0 = W + (size_t)(gc0 < CC ? gc0 : 0) * DD + kc * 4;
    const float* wp1 = W + (size_t)(gc1 < CC ? gc1 : 0) * DD + kc * 4;
    // swizzled B write offsets (elements)
    const int sxw   = ((kc >> 1) ^ ((wcol >> 1) & 3));
    const int wofs0 = wcol * 32 + sxw * 8 + (kc & 1) * 4;
    const int wofs1 = wofs0 + 1024;

    f32x4 acc[8][4] = {};
    float sq0 = 0.f, sq1 = 0.f;
    float4 na0, na1, nb0, nb1;

#define GLDS_TILE(kt, buf)                                                              \
    {                                                                                   \
        const char* gsrc = (const char*)At + (size_t)(kt) * 32768 + srcswz;             \
        _Pragma("unroll")                                                               \
        for (int c8 = 0; c8 < 8; ++c8) {                                                \
            __builtin_amdgcn_global_load_lds(                                           \
                (AS1 void*)(gsrc + c8 * 4096),                                          \
                (AS3 void*)((char*)(&As[buf][0]) + c8 * 4096 + wave * 1024),            \
                16, 0, 0);                                                              \
        }                                                                               \
    }

// pin issue order: [glds group] before [W reg loads] so vmcnt counts are exact
#define FENCE()                                                                         \
    {                                                                                   \
        __builtin_amdgcn_sched_barrier(0);                                              \
        asm volatile("" ::: "memory");                                                  \
    }

#define WAITB(n)                                                                        \
    {                                                                                   \
        asm volatile("s_waitcnt vmcnt(" #n ") lgkmcnt(0)" ::: "memory");                \
        __builtin_amdgcn_s_barrier();                                                   \
    }

#define CVT_BS(buf, v0, v1)                                                             \
    {                                                                                   \
        bf16x4 b0 = { (__bf16)(v0).x, (__bf16)(v0).y, (__bf16)(v0).z, (__bf16)(v0).w }; \
        bf16x4 b1 = { (__bf16)(v1).x, (__bf16)(v1).y, (__bf16)(v1).z, (__bf16)(v1).w }; \
        float f;                                                                        \
        f = (float)b0[0]; sq0 += f * f; f = (float)b0[1]; sq0 += f * f;                 \
        f = (float)b0[2]; sq0 += f * f; f = (float)b0[3]; sq0 += f * f;                 \
        f = (float)b1[0]; sq1 += f * f; f = (float)b1[1]; sq1 += f * f;                 \
        f = (float)b1[2]; sq1 += f * f; f = (float)b1[3]; sq1 += f * f;                 \
        *(bf16x4*)(&Bs[buf][wofs0]) = b0;                                               \
        *(bf16x4*)(&Bs[buf][wofs1]) = b1;                                               \
    }

#define COMPUTE(cur)                                                                    \
    {                                                                                   \
        bf16x8 bfrag[4];                                                                \
        _Pragma("unroll")                                                               \
        for (int j = 0; j < 4; ++j)                                                     \
            bfrag[j] = *(const bf16x8*)(&Bs[cur][j * 512 + frag_off]);                  \
        __builtin_amdgcn_s_setprio(1);                                                  \
        _Pragma("unroll")                                                               \
        for (int i = 0; i < 8; ++i) {                                                   \
            bf16x8 afrag = *(const bf16x8*)(&As[cur][wave * 4096 + i * 512 + frag_off]);\
            _Pragma("unroll")                                                           \
            for (int j = 0; j < 4; ++j)                                                 \
                acc[i][j] = __builtin_amdgcn_mfma_f32_16x16x32_bf16(afrag, bfrag[j],    \
                                                                    acc[i][j], 0, 0, 0);\
        }                                                                               \
        __builtin_amdgcn_s_setprio(0);                                                  \
    }

#define ITER(k)                                                                         \
    {                                                                                   \
        WAITB(2);                                                                       \
        GLDS_TILE((k) + 1, ((k) + 1) & 1);                                              \
        FENCE();                                                                        \
        if ((k) & 1) { nb0 = *(const float4*)(wp0 + ((k) + 2) * 32);                    \
                       nb1 = *(const float4*)(wp1 + ((k) + 2) * 32); }                  \
        else         { na0 = *(const float4*)(wp0 + ((k) + 2) * 32);                    \
                       na1 = *(const float4*)(wp1 + ((k) + 2) * 32); }                  \
        COMPUTE((k) & 1);                                                               \
        if ((k) & 1) { CVT_BS(((k) + 1) & 1, na0, na1); }                               \
        else         { CVT_BS(((k) + 1) & 1, nb0, nb1); }                               \
    }

    // ---- prologue: A(0) via glds; W(0),W(1) into regs; Bs[0] = W(0) ----
    GLDS_TILE(0, 0);
    FENCE();
    na0 = *(const float4*)(wp0);        // W(0)
    na1 = *(const float4*)(wp1);
    nb0 = *(const float4*)(wp0 + 32);   // W(1)
    nb1 = *(const float4*)(wp1 + 32);
    CVT_BS(0, na0, na1);

    // ---- k = 0 (wait: after A(0) come 4 W loads -> vmcnt(4)) ----
    WAITB(4);
    GLDS_TILE(1, 1);
    FENCE();
    na0 = *(const float4*)(wp0 + 64);   // W(2)
    na1 = *(const float4*)(wp1 + 64);
    COMPUTE(0);
    CVT_BS(1, nb0, nb1);                // W(1) -> Bs[1]

    // ---- k = 1..13 steady state (wait: after A(k) come 2 W loads -> vmcnt(2)) ----
    ITER(1);  ITER(2);  ITER(3);  ITER(4);  ITER(5);  ITER(6);  ITER(7);
    ITER(8);  ITER(9);  ITER(10); ITER(11); ITER(12); ITER(13);

    // ---- k = 14 (no W(16); A(15) issued; CVT W(15)) ----
    WAITB(2);
    GLDS_TILE(15, 1);
    COMPUTE(0);
    CVT_BS(1, nb0, nb1);                // W(15) -> Bs[1]

    // ---- k = 15 (nothing issued after A(15) -> vmcnt(0)) ----
    WAITB(0);
    COMPUTE(1);

    // column sumsq -> csq[64]
    sq0 += __shfl_xor(sq0, 1); sq1 += __shfl_xor(sq1, 1);
    sq0 += __shfl_xor(sq0, 2); sq1 += __shfl_xor(sq1, 2);
    sq0 += __shfl_xor(sq0, 4); sq1 += __shfl_xor(sq1, 4);
    if (kc == 0) { csq[wcol] = sq0; csq[wcol + 32] = sq1; }
    __syncthreads();

    // epilogue: partial sum of exp(S * cosine) per row
    const bool lastb = (cb == LASTB);
    float inv[4]; bool val[4];
    #pragma unroll
    for (int j = 0; j < 4; ++j) {
        int ct = j * 16 + m16;
        val[j] = (!lastb) || (ct < 32);   // last block has 32 valid cols
        inv[j] = rsqrtf(csq[ct]) * S_SCALE;
    }
    #pragma unroll
    for (int i = 0; i < 8; ++i) {
        #pragma unroll
        for (int r = 0; r < 4; ++r) {
            float e = 0.f;
            #pragma unroll
            for (int j = 0; j < 4; ++j)
                if (val[j]) e += __expf(acc[i][j][r] * inv[j]);
            e += __shfl_xor(e, 1);
            e += __shfl_xor(e, 2);
            e += __shfl_xor(e, 4);
            e += __shfl_xor(e, 8);
            if (m16 == 0)
                part[(size_t)cb * BD + wave * 128 + i * 16 + q * 4 + r] = e;
        }
    }
#undef GLDS_TILE
#undef FENCE
#undef WAITB
#undef CVT_BS
#undef COMPUTE
#undef ITER
}

// ---------------- Kernel 3a: parallel partial row-sums over column blocks ----------------
// 256 blocks = 8 row-groups x 32 column phases; plain stores, no atomics.
__global__ __launch_bounds__(256) void k_reduce1(const float* __restrict__ part,
                                                 float* __restrict__ rowpart) {
    const int b = blockIdx.x;
    const int rg = b >> 5, cp = b & 31;
    const int t = threadIdx.x;
    const int rl = t & 63, ph = t >> 6;     // 4 phases
    const int r0 = rg * 64;
    float s = 0.f;
    for (int c0 = cp * 4 + ph; c0 < NCB; c0 += 128)
        s += part[(size_t)c0 * BD + r0 + rl];
    __shared__ float buf[256];
    buf[t] = s;
    __syncthreads();
    if (t < 64)
        rowpart[(size_t)cp * BD + r0 + t] = buf[t] + buf[t + 64] + buf[t + 128] + buf[t + 192];
}

// ---------------- Kernel 3b: final logsumexp + label correction + mean (1 block) --------
__global__ __launch_bounds__(256) void k_final(const float* __restrict__ rowpart,
                                               const float* __restrict__ sphi,
                                               const float* __restrict__ scos,
                                               float* __restrict__ out) {
    const int t = threadIdx.x;
    float a = 0.f;
    for (int r = t; r < BD; r += 256) {
        float total = 0.f;
        #pragma unroll
        for (int cp = 0; cp < 32; ++cp)
            total += rowpart[(size_t)cp * BD + r];
        float lse = logf(total);
        float sp = sphi[r], sc = scos[r];
        float corr = log1pf(__expf(sp - lse) - __expf(sc - lse));
        a += lse + corr - sp;
    }
    for (int o = 1; o < 64; o <<= 1) a += __shfl_xor(a, o);
    __shared__ float wsum[4];
    if ((t & 63) == 0) wsum[t >> 6] = a;
    __syncthreads();
    if (t == 0) out[0] = (wsum[0] + wsum[1] + wsum[2] + wsum[3]) * (1.0f / 512.0f);
}

extern "C" void kernel_launch(void* const* d_in, const int* in_sizes, int n_in,
                              void* d_out, int out_size, void* d_ws, size_t ws_size,
                              hipStream_t stream) {
    const float* img  = (const float*)d_in[0];
    const float* prof = (const float*)d_in[1];
    const float* W    = (const float*)d_in[2];
    const int*   lab  = (const int*)d_in[3];

    char* ws = (char*)d_ws;
    __bf16* At     = (__bf16*)ws;                  // 512*512*2 = 524288 B (k-tiled)
    float* sphi    = (float*)(ws + 524288);        // 2048 B
    float* scos    = (float*)(ws + 526336);        // 2048 B
    float* part    = (float*)(ws + 528384);        // 1563*512*4 = 3,201,024 B
    float* rowpart = (float*)(ws + 3729408);       // 32*512*4 = 65,536 B

    k_prep<<<BD, 256, 0, stream>>>(img, prof, W, lab, At, sphi, scos);
    k_gemm<<<NCB, 256, 0, stream>>>(At, W, part);
    k_reduce1<<<256, 256, 0, stream>>>(part, rowpart);
    k_final<<<1, 256, 0, stream>>>(rowpart, sphi, scos, (float*)d_out);
}

// Round 2
// 325.855 us; speedup vs baseline: 1.3607x; 1.0612x over previous
//
#include <hip/hip_runtime.h>

#define S_SCALE 30.0f
#define COS_M 0.8775825618903728f
#define SIN_M 0.479425538604203f
#define TH_C (-0.8775825618903728f)
#define MM_C 0.2397127693021015f

#define BD 512
#define DD 512
#define CC 100000
#define NCB 1563            // ceil(100000/64)
#define LASTB 1562

typedef __bf16 bf16x8 __attribute__((ext_vector_type(8)));
typedef __bf16 bf16x4 __attribute__((ext_vector_type(4)));
typedef float  f32x4  __attribute__((ext_vector_type(4)));

// ---------------- Kernel 1: concat + normalize -> k-tiled bf16 A_t[16][512][32];
// one WAVE per row, no barriers, fully vectorized. Also label-column cosine/phi. ------
__global__ __launch_bounds__(256) void k_prep(const float* __restrict__ img,
                                              const float* __restrict__ prof,
                                              const float* __restrict__ W,
                                              const int* __restrict__ lab,
                                              __bf16* __restrict__ At,
                                              float* __restrict__ sphi,
                                              float* __restrict__ scos) {
    const int t = threadIdx.x;
    const int wave = t >> 6, l = t & 63;
    const int row = blockIdx.x * 4 + wave;          // 128 blocks x 4 waves = 512 rows
    const float* src = (row < 256) ? (img + (size_t)row * DD) : (prof + (size_t)(row - 256) * DD);
    float4 v0 = ((const float4*)src)[l * 2];
    float4 v1 = ((const float4*)src)[l * 2 + 1];
    float s = v0.x * v0.x + v0.y * v0.y + v0.z * v0.z + v0.w * v0.w
            + v1.x * v1.x + v1.y * v1.y + v1.z * v1.z + v1.w * v1.w;
    #pragma unroll
    for (int o = 1; o < 64; o <<= 1) s += __shfl_xor(s, o);
    float r = rsqrtf(s);
    bf16x8 a;
    a[0] = (__bf16)(v0.x * r); a[1] = (__bf16)(v0.y * r);
    a[2] = (__bf16)(v0.z * r); a[3] = (__bf16)(v0.w * r);
    a[4] = (__bf16)(v1.x * r); a[5] = (__bf16)(v1.y * r);
    a[6] = (__bf16)(v1.z * r); a[7] = (__bf16)(v1.w * r);
    // k-tiled layout: element (row, d) -> At[(d>>5)*16384 + row*32 + (d&31)]
    // lane l owns d = l*8..l*8+7  ->  kt = l>>2, inner (l&3)*8 : one bf16x8 store
    *(bf16x8*)(At + (size_t)(l >> 2) * (BD * 32) + row * 32 + (l & 3) * 8) = a;

    // label-column cosine (on bf16-truncated values, matching the GEMM)
    const int c = lab[row & 255];
    const float4* wc = (const float4*)(W + (size_t)c * DD);
    float4 w0 = wc[l * 2], w1 = wc[l * 2 + 1];
    float wb0 = (float)(__bf16)w0.x, wb1 = (float)(__bf16)w0.y;
    float wb2 = (float)(__bf16)w0.z, wb3 = (float)(__bf16)w0.w;
    float wb4 = (float)(__bf16)w1.x, wb5 = (float)(__bf16)w1.y;
    float wb6 = (float)(__bf16)w1.z, wb7 = (float)(__bf16)w1.w;
    float dot = (float)a[0] * wb0 + (float)a[1] * wb1 + (float)a[2] * wb2 + (float)a[3] * wb3
              + (float)a[4] * wb4 + (float)a[5] * wb5 + (float)a[6] * wb6 + (float)a[7] * wb7;
    float wsq = wb0 * wb0 + wb1 * wb1 + wb2 * wb2 + wb3 * wb3
              + wb4 * wb4 + wb5 * wb5 + wb6 * wb6 + wb7 * wb7;
    #pragma unroll
    for (int o = 1; o < 64; o <<= 1) { dot += __shfl_xor(dot, o); wsq += __shfl_xor(wsq, o); }
    if (l == 0) {
        float cs = dot * rsqrtf(wsq);
        float sn = sqrtf(fmaxf(0.f, fminf(1.f, 1.f - cs * cs)));
        float phi = cs * COS_M - sn * SIN_M;
        if (!(cs > TH_C)) phi = cs - MM_C;
        sphi[row] = S_SCALE * phi;
        scos[row] = S_SCALE * cs;
    }
}

// ---------------- Kernel 2: MFMA GEMM, 512 rows x 64 cols per block ----------------
// A fragments load DIRECTLY global(L2) -> registers, double-buffered 1 tile ahead.
// LDS holds only W tiles (2 x 4KB, XOR-swizzled). One barrier/tile, lgkmcnt-only wait;
// all global traffic crosses barriers with compiler-counted vmcnt (never drained).
__global__ __launch_bounds__(256, 2) void k_gemm(const __bf16* __restrict__ At,
                                                 const float* __restrict__ W,
                                                 float* __restrict__ part) {
    __shared__ __bf16 Bs[2][64 * 32];    // 2 x 4 KB
    __shared__ float  csq[64];

    const int t = threadIdx.x;
    const int cb = blockIdx.x;
    const int wave = t >> 6, lane = t & 63, q = lane >> 4, m16 = lane & 15;

    // B-fragment read offset (elements), XOR chunk swizzle (matches write side)
    const int frag_off = m16 * 32 + ((q ^ ((m16 >> 1) & 3)) << 3);

    // W staging: thread t covers (col t>>3, kc t&7) and (col 32+(t>>3), kc t&7)
    const int wcol = t >> 3, kc = t & 7;
    int gc0 = cb * 64 + wcol;
    int gc1 = gc0 + 32;
    const float* wp0 = W + (size_t)(gc0 < CC ? gc0 : 0) * DD + kc * 4;
    const float* wp1 = W + (size_t)(gc1 < CC ? gc1 : 0) * DD + kc * 4;
    const int sxw   = (kc >> 1) ^ ((wcol >> 1) & 3);
    const int wofs0 = wcol * 32 + sxw * 8 + (kc & 1) * 4;
    const int wofs1 = wofs0 + 1024;

    // A fragment pointer: rows wave*128 + i*16 + m16, k-chunk q, tile kt
    // element offset = kt*16384 + (wave*128 + i*16 + m16)*32 + q*8  (wave reads 1KB contiguous)
    const __bf16* ap = At + (size_t)(wave * 128 + m16) * 32 + q * 8;

    f32x4 acc[8][4] = {};
    float sq0 = 0.f, sq1 = 0.f;
    bf16x8 a[2][8];                      // double-buffered A fragments (64 VGPR)
    float4 wv0[16], wv1[16];             // W prefetch (static idx after full unroll)

#define CVT_BS(buf, va, vb)                                                             \
    {                                                                                   \
        bf16x4 b0 = { (__bf16)(va).x, (__bf16)(va).y, (__bf16)(va).z, (__bf16)(va).w }; \
        bf16x4 b1 = { (__bf16)(vb).x, (__bf16)(vb).y, (__bf16)(vb).z, (__bf16)(vb).w }; \
        float f;                                                                        \
        f = (float)b0[0]; sq0 += f * f; f = (float)b0[1]; sq0 += f * f;                 \
        f = (float)b0[2]; sq0 += f * f; f = (float)b0[3]; sq0 += f * f;                 \
        f = (float)b1[0]; sq1 += f * f; f = (float)b1[1]; sq1 += f * f;                 \
        f = (float)b1[2]; sq1 += f * f; f = (float)b1[3]; sq1 += f * f;                 \
        *(bf16x4*)(&Bs[buf][wofs0]) = b0;                                               \
        *(bf16x4*)(&Bs[buf][wofs1]) = b1;                                               \
    }

    // ---- prologue: A-frags(tile0) -> a[0]; W(0..2) -> regs; Bs[0] <- W(0) ----
    #pragma unroll
    for (int i = 0; i < 8; ++i)
        a[0][i] = *(const bf16x8*)(ap + i * 512);
    wv0[0] = *(const float4*)(wp0);        wv1[0] = *(const float4*)(wp1);
    wv0[1] = *(const float4*)(wp0 + 32);   wv1[1] = *(const float4*)(wp1 + 32);
    wv0[2] = *(const float4*)(wp0 + 64);   wv1[2] = *(const float4*)(wp1 + 64);
    CVT_BS(0, wv0[0], wv1[0]);

    #pragma unroll
    for (int kt = 0; kt < 16; ++kt) {
        // prefetch next A tile into the alternate register buffer (crosses the barrier)
        if (kt < 15) {
            #pragma unroll
            for (int i = 0; i < 8; ++i)
                a[(kt + 1) & 1][i] = *(const bf16x8*)(ap + (kt + 1) * 16384 + i * 512);
        }
        // W prefetch, 3 tiles deep
        if (kt + 3 < 16) {
            wv0[kt + 3] = *(const float4*)(wp0 + (kt + 3) * 32);
            wv1[kt + 3] = *(const float4*)(wp1 + (kt + 3) * 32);
        }
        // barrier guards ONLY the LDS W-tile (lgkm); global loads stay in flight
        __builtin_amdgcn_sched_barrier(0);
        asm volatile("s_waitcnt lgkmcnt(0)");
        __builtin_amdgcn_s_barrier();
        __builtin_amdgcn_sched_barrier(0);

        bf16x8 bfrag[4];
        #pragma unroll
        for (int j = 0; j < 4; ++j)
            bfrag[j] = *(const bf16x8*)(&Bs[kt & 1][j * 512 + frag_off]);

        // write next W tile AFTER the barrier (prev readers of that buffer are done)
        if (kt < 15) CVT_BS((kt + 1) & 1, wv0[kt + 1], wv1[kt + 1]);

        __builtin_amdgcn_s_setprio(1);
        #pragma unroll
        for (int i = 0; i < 8; ++i) {
            #pragma unroll
            for (int j = 0; j < 4; ++j)
                acc[i][j] = __builtin_amdgcn_mfma_f32_16x16x32_bf16(a[kt & 1][i], bfrag[j],
                                                                    acc[i][j], 0, 0, 0);
        }
        __builtin_amdgcn_s_setprio(0);
    }

    // column sumsq -> csq[64]
    sq0 += __shfl_xor(sq0, 1); sq1 += __shfl_xor(sq1, 1);
    sq0 += __shfl_xor(sq0, 2); sq1 += __shfl_xor(sq1, 2);
    sq0 += __shfl_xor(sq0, 4); sq1 += __shfl_xor(sq1, 4);
    if (kc == 0) { csq[wcol] = sq0; csq[wcol + 32] = sq1; }
    __syncthreads();

    // epilogue: partial sum of exp(S * cosine) per row
    const bool lastb = (cb == LASTB);
    float inv[4]; bool val[4];
    #pragma unroll
    for (int j = 0; j < 4; ++j) {
        int ct = j * 16 + m16;
        val[j] = (!lastb) || (ct < 32);   // last block has 32 valid cols
        inv[j] = rsqrtf(csq[ct]) * S_SCALE;
    }
    #pragma unroll
    for (int i = 0; i < 8; ++i) {
        #pragma unroll
        for (int r = 0; r < 4; ++r) {
            float e = 0.f;
            #pragma unroll
            for (int j = 0; j < 4; ++j)
                if (val[j]) e += __expf(acc[i][j][r] * inv[j]);
            e += __shfl_xor(e, 1);
            e += __shfl_xor(e, 2);
            e += __shfl_xor(e, 4);
            e += __shfl_xor(e, 8);
            if (m16 == 0)
                part[(size_t)cb * BD + wave * 128 + i * 16 + q * 4 + r] = e;
        }
    }
#undef CVT_BS
}

// ---------------- Kernel 3a: parallel partial row-sums over column blocks ----------------
__global__ __launch_bounds__(256) void k_reduce1(const float* __restrict__ part,
                                                 float* __restrict__ rowpart) {
    const int b = blockIdx.x;
    const int rg = b >> 5, cp = b & 31;
    const int t = threadIdx.x;
    const int rl = t & 63, ph = t >> 6;     // 4 phases
    const int r0 = rg * 64;
    float s = 0.f;
    for (int c0 = cp * 4 + ph; c0 < NCB; c0 += 128)
        s += part[(size_t)c0 * BD + r0 + rl];
    __shared__ float buf[256];
    buf[t] = s;
    __syncthreads();
    if (t < 64)
        rowpart[(size_t)cp * BD + r0 + t] = buf[t] + buf[t + 64] + buf[t + 128] + buf[t + 192];
}

// ---------------- Kernel 3b: final logsumexp + label correction + mean (1 block) --------
__global__ __launch_bounds__(256) void k_final(const float* __restrict__ rowpart,
                                               const float* __restrict__ sphi,
                                               const float* __restrict__ scos,
                                               float* __restrict__ out) {
    const int t = threadIdx.x;
    float a = 0.f;
    for (int r = t; r < BD; r += 256) {
        float total = 0.f;
        #pragma unroll
        for (int cp = 0; cp < 32; ++cp)
            total += rowpart[(size_t)cp * BD + r];
        float lse = logf(total);
        float sp = sphi[r], sc = scos[r];
        float corr = log1pf(__expf(sp - lse) - __expf(sc - lse));
        a += lse + corr - sp;
    }
    for (int o = 1; o < 64; o <<= 1) a += __shfl_xor(a, o);
    __shared__ float wsum[4];
    if ((t & 63) == 0) wsum[t >> 6] = a;
    __syncthreads();
    if (t == 0) out[0] = (wsum[0] + wsum[1] + wsum[2] + wsum[3]) * (1.0f / 512.0f);
}

extern "C" void kernel_launch(void* const* d_in, const int* in_sizes, int n_in,
                              void* d_out, int out_size, void* d_ws, size_t ws_size,
                              hipStream_t stream) {
    const float* img  = (const float*)d_in[0];
    const float* prof = (const float*)d_in[1];
    const float* W    = (const float*)d_in[2];
    const int*   lab  = (const int*)d_in[3];

    char* ws = (char*)d_ws;
    __bf16* At     = (__bf16*)ws;                  // 512*512*2 = 524288 B (k-tiled)
    float* sphi    = (float*)(ws + 524288);        // 2048 B
    float* scos    = (float*)(ws + 526336);        // 2048 B
    float* part    = (float*)(ws + 528384);        // 1563*512*4 = 3,201,024 B
    float* rowpart = (float*)(ws + 3729408);       // 32*512*4 = 65,536 B

    k_prep<<<128, 256, 0, stream>>>(img, prof, W, lab, At, sphi, scos);
    k_gemm<<<NCB, 256, 0, stream>>>(At, W, part);
    k_reduce1<<<256, 256, 0, stream>>>(part, rowpart);
    k_final<<<1, 256, 0, stream>>>(rowpart, sphi, scos, (float*)d_out);
}

// Round 3
// 325.637 us; speedup vs baseline: 1.3616x; 1.0007x over previous
//
#include <hip/hip_runtime.h>

#define S_SCALE 30.0f
#define COS_M 0.8775825618903728f
#define SIN_M 0.479425538604203f
#define TH_C (-0.8775825618903728f)
#define MM_C 0.2397127693021015f

#define BD 512
#define DD 512
#define CC 100000
#define NCB 1563            // ceil(100000/64)
#define LASTB 1562

typedef __bf16 bf16x8 __attribute__((ext_vector_type(8)));
typedef __bf16 bf16x4 __attribute__((ext_vector_type(4)));
typedef float  f32x4  __attribute__((ext_vector_type(4)));

// ---------------- Kernel 1: concat + normalize -> k-tiled bf16 A_t[16][512][32];
// one WAVE per row, no barriers, fully vectorized. Also label-column cosine/phi. ------
__global__ __launch_bounds__(256) void k_prep(const float* __restrict__ img,
                                              const float* __restrict__ prof,
                                              const float* __restrict__ W,
                                              const int* __restrict__ lab,
                                              __bf16* __restrict__ At,
                                              float* __restrict__ sphi,
                                              float* __restrict__ scos) {
    const int t = threadIdx.x;
    const int wave = t >> 6, l = t & 63;
    const int row = blockIdx.x * 4 + wave;          // 128 blocks x 4 waves = 512 rows
    const float* src = (row < 256) ? (img + (size_t)row * DD) : (prof + (size_t)(row - 256) * DD);
    float4 v0 = ((const float4*)src)[l * 2];
    float4 v1 = ((const float4*)src)[l * 2 + 1];
    float s = v0.x * v0.x + v0.y * v0.y + v0.z * v0.z + v0.w * v0.w
            + v1.x * v1.x + v1.y * v1.y + v1.z * v1.z + v1.w * v1.w;
    #pragma unroll
    for (int o = 1; o < 64; o <<= 1) s += __shfl_xor(s, o);
    float r = rsqrtf(s);
    bf16x8 a;
    a[0] = (__bf16)(v0.x * r); a[1] = (__bf16)(v0.y * r);
    a[2] = (__bf16)(v0.z * r); a[3] = (__bf16)(v0.w * r);
    a[4] = (__bf16)(v1.x * r); a[5] = (__bf16)(v1.y * r);
    a[6] = (__bf16)(v1.z * r); a[7] = (__bf16)(v1.w * r);
    // k-tiled layout: element (row, d) -> At[(d>>5)*16384 + row*32 + (d&31)]
    // lane l owns d = l*8..l*8+7  ->  kt = l>>2, inner (l&3)*8 : one bf16x8 store
    *(bf16x8*)(At + (size_t)(l >> 2) * (BD * 32) + row * 32 + (l & 3) * 8) = a;

    // label-column cosine (on bf16-truncated values, matching the GEMM)
    const int c = lab[row & 255];
    const float4* wc = (const float4*)(W + (size_t)c * DD);
    float4 w0 = wc[l * 2], w1 = wc[l * 2 + 1];
    float wb0 = (float)(__bf16)w0.x, wb1 = (float)(__bf16)w0.y;
    float wb2 = (float)(__bf16)w0.z, wb3 = (float)(__bf16)w0.w;
    float wb4 = (float)(__bf16)w1.x, wb5 = (float)(__bf16)w1.y;
    float wb6 = (float)(__bf16)w1.z, wb7 = (float)(__bf16)w1.w;
    float dot = (float)a[0] * wb0 + (float)a[1] * wb1 + (float)a[2] * wb2 + (float)a[3] * wb3
              + (float)a[4] * wb4 + (float)a[5] * wb5 + (float)a[6] * wb6 + (float)a[7] * wb7;
    float wsq = wb0 * wb0 + wb1 * wb1 + wb2 * wb2 + wb3 * wb3
              + wb4 * wb4 + wb5 * wb5 + wb6 * wb6 + wb7 * wb7;
    #pragma unroll
    for (int o = 1; o < 64; o <<= 1) { dot += __shfl_xor(dot, o); wsq += __shfl_xor(wsq, o); }
    if (l == 0) {
        float cs = dot * rsqrtf(wsq);
        float sn = sqrtf(fmaxf(0.f, fminf(1.f, 1.f - cs * cs)));
        float phi = cs * COS_M - sn * SIN_M;
        if (!(cs > TH_C)) phi = cs - MM_C;
        sphi[row] = S_SCALE * phi;
        scos[row] = S_SCALE * cs;
    }
}

// ---------------- Kernel 2: MFMA GEMM, 512 rows x 64 cols per block ----------------
// A fragments global(L2)->reg via a 12-slot ring (prefetch 1 tile, split issue).
// W float4 prefetch via 4-deep reg ring (~930cy cover for HBM latency).
// LDS holds only W bf16 tiles (2 x 4KB, XOR-swizzled). One barrier/tile, lgkm-only wait;
// all global traffic crosses barriers with compiler-counted vmcnt (never drained).
// CVT/ds_write of next W tile sits AFTER the MFMA cluster (W-wait overlaps MFMA).
__global__ __launch_bounds__(256, 2) void k_gemm(const __bf16* __restrict__ At,
                                                 const float* __restrict__ W,
                                                 float* __restrict__ part) {
    __shared__ __bf16 Bs[2][64 * 32];    // 2 x 4 KB
    __shared__ float  csq[64];

    const int t = threadIdx.x;
    const int cb = blockIdx.x;
    const int wave = t >> 6, lane = t & 63, q = lane >> 4, m16 = lane & 15;

    // B-fragment read offset (elements), XOR chunk swizzle (matches write side)
    const int frag_off = m16 * 32 + ((q ^ ((m16 >> 1) & 3)) << 3);

    // W staging: thread t covers (col t>>3, kc t&7) and (col 32+(t>>3), kc t&7)
    const int wcol = t >> 3, kc = t & 7;
    int gc0 = cb * 64 + wcol;
    int gc1 = gc0 + 32;
    const float* wp0 = W + (size_t)(gc0 < CC ? gc0 : 0) * DD + kc * 4;
    const float* wp1 = W + (size_t)(gc1 < CC ? gc1 : 0) * DD + kc * 4;
    const int sxw   = (kc >> 1) ^ ((wcol >> 1) & 3);
    const int wofs0 = wcol * 32 + sxw * 8 + (kc & 1) * 4;
    const int wofs1 = wofs0 + 1024;

    // A fragment pointer: rows wave*128 + i*16 + m16, k-chunk q, tile kt
    const __bf16* ap = At + (size_t)(wave * 128 + m16) * 32 + q * 8;

    f32x4 acc[8][4] = {};
    float sq0 = 0.f, sq1 = 0.f;
    bf16x8 ar[12];                       // A-frag ring: frag f of tile kt -> (kt*8+f)%12
    float4 wva[4], wvb[4];               // W ring: tile n -> slot n&3

#define CVT_BS(buf, va, vb)                                                             \
    {                                                                                   \
        bf16x4 b0 = { (__bf16)(va).x, (__bf16)(va).y, (__bf16)(va).z, (__bf16)(va).w }; \
        bf16x4 b1 = { (__bf16)(vb).x, (__bf16)(vb).y, (__bf16)(vb).z, (__bf16)(vb).w }; \
        float f;                                                                        \
        f = (float)b0[0]; sq0 += f * f; f = (float)b0[1]; sq0 += f * f;                 \
        f = (float)b0[2]; sq0 += f * f; f = (float)b0[3]; sq0 += f * f;                 \
        f = (float)b1[0]; sq1 += f * f; f = (float)b1[1]; sq1 += f * f;                 \
        f = (float)b1[2]; sq1 += f * f; f = (float)b1[3]; sq1 += f * f;                 \
        *(bf16x4*)(&Bs[buf][wofs0]) = b0;                                               \
        *(bf16x4*)(&Bs[buf][wofs1]) = b1;                                               \
    }

    // ---- prologue: A-frags(tile0) -> ring slots 0..7; W(0..3) -> ring; Bs[0] <- W(0) ----
    #pragma unroll
    for (int f = 0; f < 8; ++f)
        ar[f] = *(const bf16x8*)(ap + f * 512);
    #pragma unroll
    for (int n = 0; n < 4; ++n) {
        wva[n] = *(const float4*)(wp0 + n * 32);
        wvb[n] = *(const float4*)(wp1 + n * 32);
    }
    CVT_BS(0, wva[0], wvb[0]);

    #pragma unroll
    for (int kt = 0; kt < 16; ++kt) {
        // W prefetch 4 tiles deep (slot (kt+4)&3 == kt&3, freed by CVT at iter kt-1)
        if (kt + 4 < 16) {
            wva[(kt + 4) & 3] = *(const float4*)(wp0 + (kt + 4) * 32);
            wvb[(kt + 4) & 3] = *(const float4*)(wp1 + (kt + 4) * 32);
        }
        // A prefetch, first half (frags 0..3 of tile kt+1)
        if (kt < 15) {
            #pragma unroll
            for (int f = 0; f < 4; ++f)
                ar[((kt + 1) * 8 + f) % 12] =
                    *(const bf16x8*)(ap + (kt + 1) * 16384 + f * 512);
        }

        // barrier guards ONLY the LDS W-tile (lgkm); global loads stay in flight
        __builtin_amdgcn_sched_barrier(0);
        asm volatile("s_waitcnt lgkmcnt(0)");
        __builtin_amdgcn_s_barrier();
        __builtin_amdgcn_sched_barrier(0);

        bf16x8 bfrag[4];
        #pragma unroll
        for (int j = 0; j < 4; ++j)
            bfrag[j] = *(const bf16x8*)(&Bs[kt & 1][j * 512 + frag_off]);

        // MFMA first half (i=0..3) — consumes ring slots (kt*8+0..3)%12
        __builtin_amdgcn_s_setprio(1);
        #pragma unroll
        for (int i = 0; i < 4; ++i) {
            #pragma unroll
            for (int j = 0; j < 4; ++j)
                acc[i][j] = __builtin_amdgcn_mfma_f32_16x16x32_bf16(
                    ar[(kt * 8 + i) % 12], bfrag[j], acc[i][j], 0, 0, 0);
        }
        __builtin_amdgcn_s_setprio(0);

        // A prefetch, second half (frags 4..7 of tile kt+1) — overwrites the
        // just-consumed slots (WAR keeps ordering correct)
        if (kt < 15) {
            #pragma unroll
            for (int f = 4; f < 8; ++f)
                ar[((kt + 1) * 8 + f) % 12] =
                    *(const bf16x8*)(ap + (kt + 1) * 16384 + f * 512);
        }

        // MFMA second half (i=4..7)
        __builtin_amdgcn_s_setprio(1);
        #pragma unroll
        for (int i = 4; i < 8; ++i) {
            #pragma unroll
            for (int j = 0; j < 4; ++j)
                acc[i][j] = __builtin_amdgcn_mfma_f32_16x16x32_bf16(
                    ar[(kt * 8 + i) % 12], bfrag[j], acc[i][j], 0, 0, 0);
        }
        __builtin_amdgcn_s_setprio(0);

        // write next W tile to LDS AFTER the MFMAs (its vmcnt wait overlaps them)
        __builtin_amdgcn_sched_barrier(0);
        if (kt < 15) CVT_BS((kt + 1) & 1, wva[(kt + 1) & 3], wvb[(kt + 1) & 3]);
    }

    // column sumsq -> csq[64]
    sq0 += __shfl_xor(sq0, 1); sq1 += __shfl_xor(sq1, 1);
    sq0 += __shfl_xor(sq0, 2); sq1 += __shfl_xor(sq1, 2);
    sq0 += __shfl_xor(sq0, 4); sq1 += __shfl_xor(sq1, 4);
    if (kc == 0) { csq[wcol] = sq0; csq[wcol + 32] = sq1; }
    __syncthreads();

    // epilogue: partial sum of exp(S * cosine) per row
    const bool lastb = (cb == LASTB);
    float inv[4]; bool val[4];
    #pragma unroll
    for (int j = 0; j < 4; ++j) {
        int ct = j * 16 + m16;
        val[j] = (!lastb) || (ct < 32);   // last block has 32 valid cols
        inv[j] = rsqrtf(csq[ct]) * S_SCALE;
    }
    #pragma unroll
    for (int i = 0; i < 8; ++i) {
        #pragma unroll
        for (int r = 0; r < 4; ++r) {
            float e = 0.f;
            #pragma unroll
            for (int j = 0; j < 4; ++j)
                if (val[j]) e += __expf(acc[i][j][r] * inv[j]);
            e += __shfl_xor(e, 1);
            e += __shfl_xor(e, 2);
            e += __shfl_xor(e, 4);
            e += __shfl_xor(e, 8);
            if (m16 == 0)
                part[(size_t)cb * BD + wave * 128 + i * 16 + q * 4 + r] = e;
        }
    }
#undef CVT_BS
}

// ---------------- Kernel 3a: parallel partial row-sums over column blocks ----------------
__global__ __launch_bounds__(256) void k_reduce1(const float* __restrict__ part,
                                                 float* __restrict__ rowpart) {
    const int b = blockIdx.x;
    const int rg = b >> 5, cp = b & 31;
    const int t = threadIdx.x;
    const int rl = t & 63, ph = t >> 6;     // 4 phases
    const int r0 = rg * 64;
    float s = 0.f;
    for (int c0 = cp * 4 + ph; c0 < NCB; c0 += 128)
        s += part[(size_t)c0 * BD + r0 + rl];
    __shared__ float buf[256];
    buf[t] = s;
    __syncthreads();
    if (t < 64)
        rowpart[(size_t)cp * BD + r0 + t] = buf[t] + buf[t + 64] + buf[t + 128] + buf[t + 192];
}

// ---------------- Kernel 3b: final logsumexp + label correction + mean (1 block) --------
__global__ __launch_bounds__(256) void k_final(const float* __restrict__ rowpart,
                                               const float* __restrict__ sphi,
                                               const float* __restrict__ scos,
                                               float* __restrict__ out) {
    const int t = threadIdx.x;
    float a = 0.f;
    for (int r = t; r < BD; r += 256) {
        float total = 0.f;
        #pragma unroll
        for (int cp = 0; cp < 32; ++cp)
            total += rowpart[(size_t)cp * BD + r];
        float lse = logf(total);
        float sp = sphi[r], sc = scos[r];
        float corr = log1pf(__expf(sp - lse) - __expf(sc - lse));
        a += lse + corr - sp;
    }
    for (int o = 1; o < 64; o <<= 1) a += __shfl_xor(a, o);
    __shared__ float wsum[4];
    if ((t & 63) == 0) wsum[t >> 6] = a;
    __syncthreads();
    if (t == 0) out[0] = (wsum[0] + wsum[1] + wsum[2] + wsum[3]) * (1.0f / 512.0f);
}

extern "C" void kernel_launch(void* const* d_in, const int* in_sizes, int n_in,
                              void* d_out, int out_size, void* d_ws, size_t ws_size,
                              hipStream_t stream) {
    const float* img  = (const float*)d_in[0];
    const float* prof = (const float*)d_in[1];
    const float* W    = (const float*)d_in[2];
    const int*   lab  = (const int*)d_in[3];

    char* ws = (char*)d_ws;
    __bf16* At     = (__bf16*)ws;                  // 512*512*2 = 524288 B (k-tiled)
    float* sphi    = (float*)(ws + 524288);        // 2048 B
    float* scos    = (float*)(ws + 526336);        // 2048 B
    float* part    = (float*)(ws + 528384);        // 1563*512*4 = 3,201,024 B
    float* rowpart = (float*)(ws + 3729408);       // 32*512*4 = 65,536 B

    k_prep<<<128, 256, 0, stream>>>(img, prof, W, lab, At, sphi, scos);
    k_gemm<<<NCB, 256, 0, stream>>>(At, W, part);
    k_reduce1<<<256, 256, 0, stream>>>(part, rowpart);
    k_final<<<1, 256, 0, stream>>>(rowpart, sphi, scos, (float*)d_out);
}